// Round 4
// baseline (128.609 us; speedup 1.0000x reference)
//
#include <hip/hip_runtime.h>
#include <float.h>

using v2f = __attribute__((ext_vector_type(2))) float;
using v4f = __attribute__((ext_vector_type(4))) float;

#define EMB 10
#define STATE 20
#define HIDDEN 40
#define NPROJ 2490
#define WAVES 16
#define ITEMS 128           // items per block = 64 lanes x IPL(2)

// Score one even-aligned row pair (rows 2p, 2p+1) for TWO items per lane.
// tp is wave-uniform (derived from readfirstlane'd bounds) -> s_load path;
// the 80B pair read is amortized over 128 scores.
__device__ __forceinline__ void score_pair2(const v4f* __restrict__ tp, int p,
                                            const v2f wv[2][5],
                                            float best[2], int bidx[2]) {
    v4f a0 = tp[0], a1 = tp[1], a2 = tp[2], a3 = tp[3], a4 = tp[4];
    #pragma unroll
    for (int g = 0; g < 2; ++g) {
        v2f c0 = wv[g][0] * a0.lo;
        c0 += wv[g][1] * a0.hi; c0 += wv[g][2] * a1.lo;
        c0 += wv[g][3] * a1.hi; c0 += wv[g][4] * a2.lo;
        float s0 = c0.x + c0.y;
        v2f c1 = wv[g][0] * a2.hi;
        c1 += wv[g][1] * a3.lo; c1 += wv[g][2] * a3.hi;
        c1 += wv[g][3] * a4.lo; c1 += wv[g][4] * a4.hi;
        float s1 = c1.x + c1.y;
        float sp = s0; int ip = 2 * p;
        if (s1 > sp) { sp = s1; ip = 2 * p + 1; }   // strict > : earlier index wins
        if (sp > best[g]) { best[g] = sp; bidx[g] = ip; }
    }
}

// Geometry: 1024 threads = 16 waves, 128 items per block (lane l owns items
// l and 64+l). grid = 512 blocks -> 2 blocks/CU, 32 waves/CU: one block's
// MLP/barrier/tail phases overlap the other's scan (r3's 1 block/CU could
// not, stalling at 40% occupancy / 64% VALUBusy). Waves 0-1 compute the MLP
// -> LDS; all 16 waves scan disjoint table slices with s_load table reads.
__global__ __launch_bounds__(1024, 8) void actor_kernel(
    const int* __restrict__ wid, const int* __restrict__ pid,
    const float* __restrict__ wemb, const float* __restrict__ pemb,
    const float* __restrict__ W1, const float* __restrict__ b1,
    const float* __restrict__ W2, const float* __restrict__ b2,
    int* __restrict__ out)
{
    __shared__ v2f   sw[ITEMS][5];      // per-item layer-2 weights (5 KB)
    __shared__ float sb[WAVES][ITEMS];  // per-slice partial best (8 KB)
    __shared__ int   si[WAVES][ITEMS];  // per-slice partial argmax (8 KB)

    const int tid  = threadIdx.x;
    const int lane = tid & 63;
    const int wave = tid >> 6;
    const int itemBase = blockIdx.x * ITEMS;

    const v4f* __restrict__ tbl4 =
        (const v4f*)__builtin_assume_aligned(pemb, 16);

    if (wave < ITEMS / 64) {
        const int b = itemBase + wave * 64 + lane;
        // ---- gather x (per-lane, divergent vector loads) ----
        const int wi = wid[b];
        const int pi = pid[b];
        const float* __restrict__ wr = wemb + wi * EMB;
        const float* __restrict__ pr = pemb + pi * EMB;
        v2f x2[STATE / 2];
        #pragma unroll
        for (int k = 0; k < EMB / 2; ++k) x2[k] = *(const v2f*)(wr + 2 * k);
        #pragma unroll
        for (int k = 0; k < EMB / 2; ++k) x2[EMB / 2 + k] = *(const v2f*)(pr + 2 * k);

        // ---- layer 1 (weights uniform -> scalar loads; packed FMA) ----
        float hb[HIDDEN];
        #pragma unroll 4
        for (int j = 0; j < HIDDEN; ++j) {
            const v2f* w1r = (const v2f*)(W1 + j * STATE);
            v2f a = w1r[0] * x2[0];
            #pragma unroll
            for (int k = 1; k < STATE / 2; ++k) a += w1r[k] * x2[k];
            hb[j] = fmaxf(a.x + a.y + b1[j], 0.0f);
        }
        v2f h2[HIDDEN / 2];
        #pragma unroll
        for (int k = 0; k < HIDDEN / 2; ++k) h2[k] = (v2f){hb[2 * k], hb[2 * k + 1]};

        // ---- layer 2 -> LDS ----
        #pragma unroll
        for (int d = 0; d < EMB; d += 2) {
            const v2f* w2r0 = (const v2f*)(W2 + d * HIDDEN);
            const v2f* w2r1 = (const v2f*)(W2 + (d + 1) * HIDDEN);
            v2f a0 = w2r0[0] * h2[0];
            v2f a1 = w2r1[0] * h2[0];
            #pragma unroll
            for (int k = 1; k < HIDDEN / 2; ++k) { a0 += w2r0[k] * h2[k]; a1 += w2r1[k] * h2[k]; }
            sw[wave * 64 + lane][d / 2] = (v2f){a0.x + a0.y + b2[d], a1.x + a1.y + b2[d + 1]};
        }
    }
    __syncthreads();

    // ---- each lane picks up weights for its 2 items ----
    v2f wv[2][5];
    #pragma unroll
    for (int g = 0; g < 2; ++g) {
        #pragma unroll
        for (int k = 0; k < 5; ++k) wv[g][k] = sw[g * 64 + lane][k];
    }

    float best[2];
    int   bidx[2];
    #pragma unroll
    for (int g = 0; g < 2; ++g) { best[g] = -FLT_MAX; bidx[g] = 1; }

    if (wave == 0) {
        // row 1 alone (row 0 excluded from the table): 8B-aligned loads
        v2f c0v = *(const v2f*)(pemb + 10);
        v4f c1v = *(const v4f*)(pemb + 12);
        v4f c2v = *(const v4f*)(pemb + 16);
        #pragma unroll
        for (int g = 0; g < 2; ++g) {
            v2f a = wv[g][0] * c0v;
            a += wv[g][1] * c1v.lo; a += wv[g][2] * c1v.hi;
            a += wv[g][3] * c2v.lo; a += wv[g][4] * c2v.hi;
            best[g] = a.x + a.y; bidx[g] = 1;
        }
    }

    // pairs p in [1,1245): rows (2p,2p+1). 1244 pairs, 16 slices in ascending
    // order (slices 0-11: 78 pairs, 12-15: 77). Bounds are runtime but forced
    // wave-uniform via readfirstlane -> SGPR loop -> s_load table reads.
    int start = (wave < 12) ? (1 + 78 * wave) : (937 + 77 * (wave - 12));
    int cnt   = (wave < 12) ? 78 : 77;
    start = __builtin_amdgcn_readfirstlane(start);
    cnt   = __builtin_amdgcn_readfirstlane(cnt);

    const v4f* tp = tbl4 + start * 5;
    #pragma unroll 4
    for (int i = 0; i < cnt; ++i, tp += 5)
        score_pair2(tp, start + i, wv, best, bidx);

    // ---- write per-slice partials (ascending slice -> strict > keeps ties) ----
    #pragma unroll
    for (int g = 0; g < 2; ++g) {
        sb[wave][g * 64 + lane] = best[g];
        si[wave][g * 64 + lane] = bidx[g];
    }
    __syncthreads();

    if (tid < ITEMS) {
        float bb = sb[0][tid];
        int   bi = si[0][tid];
        #pragma unroll
        for (int w = 1; w < WAVES; ++w) {
            float v  = sb[w][tid];
            int   vi = si[w][tid];
            if (v > bb) { bb = v; bi = vi; }
        }
        out[itemBase + tid] = bi;
    }
}

extern "C" void kernel_launch(void* const* d_in, const int* in_sizes, int n_in,
                              void* d_out, int out_size, void* d_ws, size_t ws_size,
                              hipStream_t stream) {
    const int*   wid  = (const int*)  d_in[0];
    const int*   pid  = (const int*)  d_in[1];
    const float* wemb = (const float*)d_in[2];
    const float* pemb = (const float*)d_in[3];
    const float* W1   = (const float*)d_in[4];
    const float* b1   = (const float*)d_in[5];
    const float* W2   = (const float*)d_in[6];
    const float* b2   = (const float*)d_in[7];
    int* out = (int*)d_out;

    const int B = in_sizes[0];               // 65536
    actor_kernel<<<B / ITEMS, 1024, 0, stream>>>(wid, pid, wemb, pemb, W1, b1, W2, b2, out);
}